// Round 2
// baseline (23931.544 us; speedup 1.0000x reference)
//
#include <hip/hip_runtime.h>
#include <stdint.h>

#define T_STEPS 512
#define NGRP 16u

typedef short short8 __attribute__((ext_vector_type(8)));
typedef float f32x4 __attribute__((ext_vector_type(4)));

// ---- ws layout (bytes) ----
#define OFF_DONE1 0                       // [512][16] counters, 64B padded = 512 KB
#define OFF_DONE2 (512 * 1024)            // [512] counters, 64B padded = 32 KB
#define OFF_HBUF0 (OFF_DONE2 + 512 * 64)  // 64*1024 bf16 = 128 KB
#define OFF_HBUF1 (OFF_HBUF0 + 64 * 1024 * 2)
#define OFF_XBF   (OFF_HBUF1 + 64 * 1024 * 2)      // = 819200; [512][64][512] bf16 = 32 MB
#define OFF_WPACK (OFF_XBF + 512 * 64 * 512 * 2)   // [4096][1536] bf16 = 12 MB
#define MEMSET_BYTES OFF_XBF

// LDS strides (shorts): dword stride % 32 == 8 -> exact 2-way bank aliasing (free)
#define AX_STR 528
#define AH_STR 1040

__device__ __forceinline__ unsigned short f2bf(float f) {
  unsigned u = __float_as_uint(f);
  u += 0x7fffu + ((u >> 16) & 1u);   // RNE (inputs are finite randoms)
  return (unsigned short)(u >> 16);
}

__device__ __forceinline__ void g2l16(const void* g, void* l) {
  // 16B per lane, wave-cooperative DMA global->LDS
  __builtin_amdgcn_global_load_lds(
      (const __attribute__((address_space(1))) void*)g,
      (__attribute__((address_space(3))) void*)l,
      16, 0, 0);
}

// ---- prep: x [B][T][D] f32 -> xbf [T][B][D] bf16 ----
__global__ __launch_bounds__(256) void k_xconv(const float* __restrict__ x,
                                               unsigned short* __restrict__ xbf) {
  int g = blockIdx.x * 256 + threadIdx.x;   // 2,097,152 threads, 8 elems each
  int d8 = g & 63;
  int b = (g >> 6) & 63;
  int t = g >> 12;
  const float* src = x + (((size_t)b * 512 + t) * 512 + d8 * 8);
  float4 v0 = *(const float4*)src;
  float4 v1 = *(const float4*)(src + 4);
  short8 o;
  o[0] = (short)f2bf(v0.x); o[1] = (short)f2bf(v0.y);
  o[2] = (short)f2bf(v0.z); o[3] = (short)f2bf(v0.w);
  o[4] = (short)f2bf(v1.x); o[5] = (short)f2bf(v1.y);
  o[6] = (short)f2bf(v1.z); o[7] = (short)f2bf(v1.w);
  *(short8*)(xbf + (((size_t)t * 64 + b) * 512 + d8 * 8)) = o;
}

// ---- prep: W [k][col] f32 -> Wpack [colpack][k] bf16 (B-fragment friendly) ----
// colpack = cg*64 + gate*16 + ul  for col = gate*1024 + cg*16 + ul
__global__ __launch_bounds__(256) void k_wpack(const float* __restrict__ Wx,
                                               const float* __restrict__ Wh,
                                               unsigned short* __restrict__ wp) {
  __shared__ unsigned short tile[64 * 68];
  int tid = threadIdx.x, lane = tid & 63, wave = tid >> 6;
  int kt = blockIdx.x >> 6;   // 0..23
  int ct = blockIdx.x & 63;   // 0..63
  int K0 = kt * 64, C0 = ct * 64;
  const float* src = (K0 < 512) ? (Wx + (size_t)K0 * 4096)
                                : (Wh + (size_t)(K0 - 512) * 4096);
  #pragma unroll
  for (int i = 0; i < 16; ++i) {
    int kl = i * 4 + wave;
    float v = src[(size_t)kl * 4096 + C0 + lane];
    tile[lane * 68 + kl] = f2bf(v);     // transposed store
  }
  __syncthreads();
  #pragma unroll
  for (int i = 0; i < 16; ++i) {
    int c = i * 4 + wave;
    int col = C0 + c;
    int gg = col >> 10, idx = col & 1023;
    int cp = (idx >> 4) * 64 + gg * 16 + (idx & 15);
    wp[(size_t)cp * 1536 + K0 + lane] = tile[c * 68 + lane];
  }
}

// ---- persistent scan kernel ----
// 256 blocks x 256 threads. block: mg = blockIdx&3 (16 batch rows), cg = blockIdx>>2 (16 u's).
// wave w handles gate w (16 cols), M=16 rows, K=1536. B-frags resident in VGPRs.
__global__ __launch_bounds__(256, 1) void k_scan(
    const unsigned short* __restrict__ xbf,
    const unsigned short* __restrict__ wp,
    const float* __restrict__ bias,
    float* __restrict__ out,
    unsigned* __restrict__ done1,
    unsigned* __restrict__ done2,
    unsigned short* __restrict__ hb0,
    unsigned short* __restrict__ hb1) {
  __shared__ __align__(16) unsigned short Ax[16 * AX_STR];
  __shared__ __align__(16) unsigned short Ah[16 * AH_STR];
  __shared__ float Gs[4 * 320];

  const int tid = threadIdx.x;
  const int lane = tid & 63;
  const int wave = tid >> 6;
  const int mg = blockIdx.x & 3;
  const int cg = blockIdx.x >> 2;
  const int grp = blockIdx.x >> 4;   // 16 groups of 16
  const int arow = lane & 15;
  const int quad = lane >> 4;

  // preload weight B-fragments for this wave's 16 cols: 48 frags = 192 VGPRs.
  // VOLATILE: forbids the compiler from sinking these loads into the t-loop
  // (R1 post-mortem: VGPR_Count=128 proved remat-per-step -> ~50 GB LLC traffic).
  short8 wf[48];
  {
    const volatile short8* wbase = (const volatile short8*)(
        wp + (size_t)(cg * 64 + wave * 16 + arow) * 1536 + quad * 8);
    #pragma unroll
    for (int kk = 0; kk < 48; ++kk)
      wf[kk] = wbase[kk * 4];   // kk*32 shorts = kk*4 short8
  }
  const int u = tid & 15, m = tid >> 4;
  const int ug = cg * 16 + u;
  const float bi = bias[ug], bff = bias[1024 + ug];
  const float bc = bias[2048 + ug], bo = bias[3072 + ug];
  float c_state = 0.f;

  #pragma unroll 1
  for (int t = 0; t < T_STEPS; ++t) {
    // ---- stage x rows (no h dependency; overlaps barrier slack) ----
    const unsigned short* xsrc = xbf + ((size_t)t * 64 + mg * 16) * 512;
    #pragma unroll
    for (int r = 0; r < 4; ++r) {
      int row = wave * 4 + r;
      g2l16(xsrc + (size_t)row * 512 + lane * 8, &Ax[row * AX_STR]);
    }
    __syncthreads();
    f32x4 acc = {0.f, 0.f, 0.f, 0.f};
    #pragma unroll
    for (int kk = 0; kk < 16; ++kk) {
      short8 a = *(const short8*)&Ax[arow * AX_STR + kk * 32 + quad * 8];
      acc = __builtin_amdgcn_mfma_f32_16x16x32_bf16(a, wf[kk], acc, 0, 0, 0);
    }
    // ---- wait for h_{t-1} ----
    if (t > 0 && tid == 0) {
      while (__hip_atomic_load(&done2[(t - 1) * 16], __ATOMIC_ACQUIRE,
                               __HIP_MEMORY_SCOPE_AGENT) < NGRP)
        __builtin_amdgcn_s_sleep(1);
    }
    __syncthreads();
    __threadfence();   // acquire: invalidate caches before reading fresh h
    const unsigned short* hsrc =
        ((t & 1) ? hb0 : hb1) + (size_t)mg * 16 * 1024;
    #pragma unroll
    for (int r = 0; r < 4; ++r) {
      int row = wave * 4 + r;
      g2l16(hsrc + (size_t)row * 1024 + lane * 8, &Ah[row * AH_STR]);
      g2l16(hsrc + (size_t)row * 1024 + 512 + lane * 8, &Ah[row * AH_STR + 512]);
    }
    __syncthreads();
    #pragma unroll
    for (int kk = 0; kk < 32; ++kk) {
      short8 a = *(const short8*)&Ah[arow * AH_STR + kk * 32 + quad * 8];
      acc = __builtin_amdgcn_mfma_f32_16x16x32_bf16(a, wf[16 + kk], acc, 0, 0, 0);
    }
    // ---- gates to LDS (C/D layout: col=lane&15, row=quad*4+r) ----
    #pragma unroll
    for (int r = 0; r < 4; ++r)
      Gs[wave * 320 + (quad * 4 + r) * 20 + arow] = acc[r];
    __syncthreads();
    // ---- per-(m,u) gate math; 256 threads = 16 rows x 16 u ----
    float gi = Gs[m * 20 + u] + bi;
    float gf = Gs[320 + m * 20 + u] + bff;
    float gc = Gs[640 + m * 20 + u] + bc;
    float go = Gs[960 + m * 20 + u] + bo;
    float ig = 1.f / (1.f + __expf(-gi));
    float fg = 1.f / (1.f + __expf(-gf));
    float og = 1.f / (1.f + __expf(-go));
    float cb = tanhf(gc);
    c_state = fg * c_state + ig * cb;
    float h = og * tanhf(c_state);
    unsigned short* hdst = (t & 1) ? hb1 : hb0;
    // nontemporal: bypass L2 so the release fence has no dirty lines to write back
    __builtin_nontemporal_store(f2bf(h),
        hdst + (size_t)(mg * 16 + m) * 1024 + cg * 16 + u);
    if (t == T_STEPS - 1) {
      float* orow = out + (size_t)(mg * 16 + m) * 3072 + cg * 16 + u;
      orow[0] = h;
      orow[1024] = h;
      orow[2048] = c_state;
    }
    __threadfence();   // publish h stores (device scope)
    __syncthreads();
    if (tid == 0) {
      unsigned prev = __hip_atomic_fetch_add(&done1[(t * 16 + grp) * 16], 1u,
                                             __ATOMIC_ACQ_REL,
                                             __HIP_MEMORY_SCOPE_AGENT);
      if (prev == NGRP - 1)
        __hip_atomic_fetch_add(&done2[t * 16], 1u, __ATOMIC_ACQ_REL,
                               __HIP_MEMORY_SCOPE_AGENT);
    }
  }
}

extern "C" void kernel_launch(void* const* d_in, const int* in_sizes, int n_in,
                              void* d_out, int out_size, void* d_ws, size_t ws_size,
                              hipStream_t stream) {
  const float* x  = (const float*)d_in[0];
  const float* Wx = (const float*)d_in[1];
  const float* Wh = (const float*)d_in[2];
  const float* b  = (const float*)d_in[3];
  float* out = (float*)d_out;
  char* ws = (char*)d_ws;
  unsigned* done1 = (unsigned*)(ws + OFF_DONE1);
  unsigned* done2 = (unsigned*)(ws + OFF_DONE2);
  unsigned short* hb0 = (unsigned short*)(ws + OFF_HBUF0);
  unsigned short* hb1 = (unsigned short*)(ws + OFF_HBUF1);
  unsigned short* xbf = (unsigned short*)(ws + OFF_XBF);
  unsigned short* wp  = (unsigned short*)(ws + OFF_WPACK);

  // zero barrier counters + h double-buffer (ws is poisoned each call)
  hipMemsetAsync(d_ws, 0, MEMSET_BYTES, stream);
  k_xconv<<<8192, 256, 0, stream>>>(x, xbf);
  k_wpack<<<1536, 256, 0, stream>>>(Wx, Wh, wp);

  void* args[] = {&xbf, &wp, &b, &out, &done1, &done2, &hb0, &hb1};
  hipLaunchCooperativeKernel((void*)k_scan, dim3(256), dim3(256), args, 0, stream);
}

// Round 3
// 10042.104 us; speedup vs baseline: 2.3831x; 2.3831x over previous
//
#include <hip/hip_runtime.h>
#include <stdint.h>

#define T_STEPS 512
#define NGRP 16u

typedef short short8 __attribute__((ext_vector_type(8)));
typedef float f32x4 __attribute__((ext_vector_type(4)));

// ---- ws layout (bytes) ----
#define OFF_DONE1 0                       // [512][16] counters, 64B padded = 512 KB
#define OFF_DONE2 (512 * 1024)            // [512] counters, 64B padded = 32 KB
#define OFF_HBUF0 (OFF_DONE2 + 512 * 64)  // 64*1024 bf16 = 128 KB
#define OFF_HBUF1 (OFF_HBUF0 + 64 * 1024 * 2)
#define OFF_XBF   (OFF_HBUF1 + 64 * 1024 * 2)      // [512][64][512] bf16 = 32 MB
#define OFF_WPACK (OFF_XBF + 512 * 64 * 512 * 2)   // [4096][1536] bf16 = 12 MB
#define MEMSET_BYTES OFF_XBF

// LDS strides (shorts)
#define W_STR 1544   // 772 dw, %32==4 -> 2-way on 16-col B-frag reads (free)
#define A_STR 536    // 268 dw, %32==12 -> 2-way on 16-row A-frag reads (free)
#define G_STR 17

__device__ __forceinline__ unsigned short f2bf(float f) {
  unsigned u = __float_as_uint(f);
  u += 0x7fffu + ((u >> 16) & 1u);   // RNE
  return (unsigned short)(u >> 16);
}

__device__ __forceinline__ void g2l16(const void* g, void* l) {
  __builtin_amdgcn_global_load_lds(
      (const __attribute__((address_space(1))) void*)g,
      (__attribute__((address_space(3))) void*)l,
      16, 0, 0);
}

// ---- prep: x [B][T][D] f32 -> xbf [T][B][D] bf16 ----
__global__ __launch_bounds__(256) void k_xconv(const float* __restrict__ x,
                                               unsigned short* __restrict__ xbf) {
  int g = blockIdx.x * 256 + threadIdx.x;
  int d8 = g & 63;
  int b = (g >> 6) & 63;
  int t = g >> 12;
  const float* src = x + (((size_t)b * 512 + t) * 512 + d8 * 8);
  float4 v0 = *(const float4*)src;
  float4 v1 = *(const float4*)(src + 4);
  short8 o;
  o[0] = (short)f2bf(v0.x); o[1] = (short)f2bf(v0.y);
  o[2] = (short)f2bf(v0.z); o[3] = (short)f2bf(v0.w);
  o[4] = (short)f2bf(v1.x); o[5] = (short)f2bf(v1.y);
  o[6] = (short)f2bf(v1.z); o[7] = (short)f2bf(v1.w);
  *(short8*)(xbf + (((size_t)t * 64 + b) * 512 + d8 * 8)) = o;
}

// ---- prep: W [k][col] f32 -> wp [colpack][k] bf16 ----
// col = g*1024 + u  ->  cp = (u>>2)*16 + g*4 + (u&3)   (block bc owns cp rows bc*16..bc*16+15)
__global__ __launch_bounds__(256) void k_wpack(const float* __restrict__ Wx,
                                               const float* __restrict__ Wh,
                                               unsigned short* __restrict__ wp) {
  __shared__ unsigned short tile[64 * 68];
  int tid = threadIdx.x, lane = tid & 63, wave = tid >> 6;
  int kt = blockIdx.x >> 6;   // 0..23
  int ct = blockIdx.x & 63;   // 0..63
  int K0 = kt * 64, C0 = ct * 64;
  const float* src = (K0 < 512) ? (Wx + (size_t)K0 * 4096)
                                : (Wh + (size_t)(K0 - 512) * 4096);
  #pragma unroll
  for (int i = 0; i < 16; ++i) {
    int kl = i * 4 + wave;
    float v = src[(size_t)kl * 4096 + C0 + lane];
    tile[lane * 68 + kl] = f2bf(v);
  }
  __syncthreads();
  #pragma unroll
  for (int i = 0; i < 16; ++i) {
    int c = i * 4 + wave;
    int col = C0 + c;
    int gg = col >> 10, idx = col & 1023;
    int cp = (idx >> 2) * 16 + gg * 4 + (idx & 3);
    wp[(size_t)cp * 1536 + K0 + lane] = tile[c * 68 + lane];
  }
}

// ---- persistent scan ----
// 256 blocks x 256 threads; block bc owns 4 units (16 cols = 4 gates x 4 u).
// Weights LDS-resident. Wave w: kh = w&1 (K-half of each 512-chunk), rt_rel = w>>1.
__global__ __launch_bounds__(256, 1) void k_scan(
    const unsigned short* __restrict__ xbf,
    const unsigned short* __restrict__ wp,
    const float* __restrict__ bias,
    float* __restrict__ out,
    unsigned* __restrict__ done1,
    unsigned* __restrict__ done2,
    unsigned short* __restrict__ hb0,
    unsigned short* __restrict__ hb1) {
  __shared__ __align__(16) unsigned short Wlds[16 * W_STR];   // 49.4 KB
  __shared__ __align__(16) unsigned short Ab[2][32 * A_STR];  // 2x34.3 KB
  __shared__ float Gs[2][64 * G_STR];                         // 8.7 KB

  const int tid = threadIdx.x;
  const int lane = tid & 63;
  const int wave = tid >> 6;
  const int bc = blockIdx.x;
  const int grp = bc >> 4;          // 16 groups of 16
  const int arow = lane & 15;
  const int quad = lane >> 4;
  const int kh = wave & 1;
  const int rt_rel = wave >> 1;

  // one-time: weights -> LDS (16 rows x 1536, padded stride)
  for (int i = tid; i < 16 * 192; i += 256) {
    int row = i / 192, o = i % 192;
    *(short8*)&Wlds[row * W_STR + o * 8] =
        *(const short8*)&wp[((size_t)bc * 16 + row) * 1536 + o * 8];
  }

  const int m = tid >> 2, ul = tid & 3;
  const int ug = bc * 4 + ul;
  const float bi = bias[ug], bff = bias[1024 + ug];
  const float bc_ = bias[2048 + ug], bo = bias[3072 + ug];
  float c_state = 0.f;
  __syncthreads();

  #pragma unroll 1
  for (int t = 0; t < T_STEPS; ++t) {
    f32x4 acc[2] = {{0.f, 0.f, 0.f, 0.f}, {0.f, 0.f, 0.f, 0.f}};

    // ---- X phase (no h dependency; overlaps barrier propagation) ----
    const unsigned short* xsrc = xbf + (size_t)t * 64 * 512;
    #pragma unroll
    for (int r = 0; r < 8; ++r) {   // rows 0..31 -> Ab[0]
      int row = wave * 8 + r;
      g2l16(xsrc + (size_t)row * 512 + lane * 8, &Ab[0][row * A_STR]);
    }
    #pragma unroll
    for (int r = 0; r < 8; ++r) {   // rows 32..63 -> Ab[1]
      int row = wave * 8 + r;
      g2l16(xsrc + (size_t)(32 + row) * 512 + lane * 8, &Ab[1][row * A_STR]);
    }
    __syncthreads();
    #pragma unroll
    for (int rh = 0; rh < 2; ++rh) {
      const unsigned short* Ap = &Ab[rh][(rt_rel * 16 + arow) * A_STR + kh * 256 + quad * 8];
      const unsigned short* Bp = &Wlds[arow * W_STR + kh * 256 + quad * 8];
      #pragma unroll
      for (int j = 0; j < 8; ++j) {
        short8 a = *(const short8*)(Ap + j * 32);
        short8 b = *(const short8*)(Bp + j * 32);
        acc[rh] = __builtin_amdgcn_mfma_f32_16x16x32_bf16(a, b, acc[rh], 0, 0, 0);
      }
    }

    // ---- wait for h_{t-1}: RELAXED spin (no per-poll cache maintenance) ----
    if (t > 0 && tid == 0) {
      while (__hip_atomic_load(&done2[(t - 1) * 16], __ATOMIC_RELAXED,
                               __HIP_MEMORY_SCOPE_AGENT) != NGRP)
        __builtin_amdgcn_s_sleep(1);
    }
    __syncthreads();
    __builtin_amdgcn_fence(__ATOMIC_ACQUIRE, "agent");   // one inv per wave per step

    // ---- H phase: 4 chunks (row-half rh, k-slice ks), double-buffered ----
    const unsigned short* hsrc = (t & 1) ? hb0 : hb1;
    // stage (rh0,ks0) -> Ab[0]
    #pragma unroll
    for (int r = 0; r < 8; ++r) {
      int row = wave * 8 + r;
      g2l16(hsrc + (size_t)row * 1024 + lane * 8, &Ab[0][row * A_STR]);
    }
    __syncthreads();
    #pragma unroll
    for (int ph = 0; ph < 4; ++ph) {
      // stage next chunk (ph+1) into the other buffer
      if (ph < 3) {
        int nrh = (ph + 1) >> 1, nks = (ph + 1) & 1;
        #pragma unroll
        for (int r = 0; r < 8; ++r) {
          int row = wave * 8 + r;
          g2l16(hsrc + (size_t)(nrh * 32 + row) * 1024 + nks * 512 + lane * 8,
                &Ab[(ph + 1) & 1][row * A_STR]);
        }
      }
      // compute chunk ph from Ab[ph&1]
      int rh = ph >> 1, ks = ph & 1;
      const unsigned short* Ap = &Ab[ph & 1][(rt_rel * 16 + arow) * A_STR + kh * 256 + quad * 8];
      const unsigned short* Bp = &Wlds[arow * W_STR + 512 + ks * 512 + kh * 256 + quad * 8];
      #pragma unroll
      for (int j = 0; j < 8; ++j) {
        short8 a = *(const short8*)(Ap + j * 32);
        short8 b = *(const short8*)(Bp + j * 32);
        acc[rh] = __builtin_amdgcn_mfma_f32_16x16x32_bf16(a, b, acc[rh], 0, 0, 0);
      }
      __syncthreads();
    }

    // ---- gates to LDS: C/D layout col=lane&15, row=quad*4+r ----
    #pragma unroll
    for (int rh = 0; rh < 2; ++rh)
      #pragma unroll
      for (int r = 0; r < 4; ++r)
        Gs[kh][(rh * 32 + rt_rel * 16 + quad * 4 + r) * G_STR + arow] = acc[rh][r];
    __syncthreads();

    // ---- gate math: thread = (m = tid>>2, ul = tid&3) ----
    float gi = Gs[0][m * G_STR + ul]      + Gs[1][m * G_STR + ul]      + bi;
    float gf = Gs[0][m * G_STR + 4 + ul]  + Gs[1][m * G_STR + 4 + ul]  + bff;
    float gc = Gs[0][m * G_STR + 8 + ul]  + Gs[1][m * G_STR + 8 + ul]  + bc_;
    float go = Gs[0][m * G_STR + 12 + ul] + Gs[1][m * G_STR + 12 + ul] + bo;
    float ig = 1.f / (1.f + __expf(-gi));
    float fg = 1.f / (1.f + __expf(-gf));
    float og = 1.f / (1.f + __expf(-go));
    float cb = tanhf(gc);
    c_state = fg * c_state + ig * cb;
    float h = og * tanhf(c_state);
    unsigned short* hdst = (t & 1) ? hb1 : hb0;
    hdst[(size_t)m * 1024 + ug] = f2bf(h);
    if (t == T_STEPS - 1) {
      float* orow = out + (size_t)m * 3072 + ug;
      orow[0] = h;
      orow[1024] = h;
      orow[2048] = c_state;
    }
    __syncthreads();   // drains vmcnt: all h stores in L2 before release
    if (tid == 0) {
      __builtin_amdgcn_fence(__ATOMIC_RELEASE, "agent");  // one wbl2 per block per step
      unsigned prev = __hip_atomic_fetch_add(&done1[(t * 16 + grp) * 16], 1u,
                                             __ATOMIC_RELAXED,
                                             __HIP_MEMORY_SCOPE_AGENT);
      if (prev == NGRP - 1)
        __hip_atomic_fetch_add(&done2[t * 16], 1u, __ATOMIC_RELEASE,
                               __HIP_MEMORY_SCOPE_AGENT);
    }
  }
}

extern "C" void kernel_launch(void* const* d_in, const int* in_sizes, int n_in,
                              void* d_out, int out_size, void* d_ws, size_t ws_size,
                              hipStream_t stream) {
  const float* x  = (const float*)d_in[0];
  const float* Wx = (const float*)d_in[1];
  const float* Wh = (const float*)d_in[2];
  const float* b  = (const float*)d_in[3];
  float* out = (float*)d_out;
  char* ws = (char*)d_ws;
  unsigned* done1 = (unsigned*)(ws + OFF_DONE1);
  unsigned* done2 = (unsigned*)(ws + OFF_DONE2);
  unsigned short* hb0 = (unsigned short*)(ws + OFF_HBUF0);
  unsigned short* hb1 = (unsigned short*)(ws + OFF_HBUF1);
  unsigned short* xbf = (unsigned short*)(ws + OFF_XBF);
  unsigned short* wp  = (unsigned short*)(ws + OFF_WPACK);

  hipMemsetAsync(d_ws, 0, MEMSET_BYTES, stream);
  k_xconv<<<8192, 256, 0, stream>>>(x, xbf);
  k_wpack<<<1536, 256, 0, stream>>>(Wx, Wh, wp);

  void* args[] = {&xbf, &wp, &b, &out, &done1, &done2, &hb0, &hb1};
  hipLaunchCooperativeKernel((void*)k_scan, dim3(256), dim3(256), args, 0, stream);
}

// Round 4
// 3007.966 us; speedup vs baseline: 7.9561x; 3.3385x over previous
//
#include <hip/hip_runtime.h>
#include <stdint.h>

#define T_STEPS 512
#define NGRP 16u
#define RING 16
#define SLOT_SHORTS (64 * 1024)   // one h slot: 64x1024 bf16 = 128 KB

typedef short short8 __attribute__((ext_vector_type(8)));
typedef float f32x4 __attribute__((ext_vector_type(4)));

// ---- ws layout (bytes) ----
#define OFF_DONE1 0                        // [512][16] counters, 64B padded = 512 KB
#define OFF_DONE2 (512 * 1024)             // [512] counters, 64B padded = 32 KB
#define OFF_HRING (OFF_DONE2 + 512 * 64)   // 16 slots x 128 KB = 2 MB
#define OFF_XBF   (OFF_HRING + RING * SLOT_SHORTS * 2)   // [512][64][512] bf16 = 32 MB
#define OFF_WPACK (OFF_XBF + 512 * 64 * 512 * 2)         // [4096][1536] bf16 = 12 MB
#define MEMSET_BYTES (OFF_HRING + SLOT_SHORTS * 2)       // counters + ring slot 0 (h_{-1}=0)

// LDS strides (shorts)
#define W_STR 1544
#define A_STR 536
#define G_STR 17

__device__ __forceinline__ unsigned short f2bf(float f) {
  unsigned u = __float_as_uint(f);
  u += 0x7fffu + ((u >> 16) & 1u);   // RNE
  return (unsigned short)(u >> 16);
}

__device__ __forceinline__ void g2l16(const void* g, void* l) {
  __builtin_amdgcn_global_load_lds(
      (const __attribute__((address_space(1))) void*)g,
      (__attribute__((address_space(3))) void*)l,
      16, 0, 0);
}

// ---- prep: x [B][T][D] f32 -> xbf [T][B][D] bf16 ----
__global__ __launch_bounds__(256) void k_xconv(const float* __restrict__ x,
                                               unsigned short* __restrict__ xbf) {
  int g = blockIdx.x * 256 + threadIdx.x;
  int d8 = g & 63;
  int b = (g >> 6) & 63;
  int t = g >> 12;
  const float* src = x + (((size_t)b * 512 + t) * 512 + d8 * 8);
  float4 v0 = *(const float4*)src;
  float4 v1 = *(const float4*)(src + 4);
  short8 o;
  o[0] = (short)f2bf(v0.x); o[1] = (short)f2bf(v0.y);
  o[2] = (short)f2bf(v0.z); o[3] = (short)f2bf(v0.w);
  o[4] = (short)f2bf(v1.x); o[5] = (short)f2bf(v1.y);
  o[6] = (short)f2bf(v1.z); o[7] = (short)f2bf(v1.w);
  *(short8*)(xbf + (((size_t)t * 64 + b) * 512 + d8 * 8)) = o;
}

// ---- prep: W [k][col] f32 -> wp [colpack][k] bf16 ----
// col = g*1024 + u  ->  cp = (u>>2)*16 + g*4 + (u&3)
__global__ __launch_bounds__(256) void k_wpack(const float* __restrict__ Wx,
                                               const float* __restrict__ Wh,
                                               unsigned short* __restrict__ wp) {
  __shared__ unsigned short tile[64 * 68];
  int tid = threadIdx.x, lane = tid & 63, wave = tid >> 6;
  int kt = blockIdx.x >> 6;
  int ct = blockIdx.x & 63;
  int K0 = kt * 64, C0 = ct * 64;
  const float* src = (K0 < 512) ? (Wx + (size_t)K0 * 4096)
                                : (Wh + (size_t)(K0 - 512) * 4096);
  #pragma unroll
  for (int i = 0; i < 16; ++i) {
    int kl = i * 4 + wave;
    float v = src[(size_t)kl * 4096 + C0 + lane];
    tile[lane * 68 + kl] = f2bf(v);
  }
  __syncthreads();
  #pragma unroll
  for (int i = 0; i < 16; ++i) {
    int c = i * 4 + wave;
    int col = C0 + c;
    int gg = col >> 10, idx = col & 1023;
    int cp = (idx >> 2) * 16 + gg * 4 + (idx & 3);
    wp[(size_t)cp * 1536 + K0 + lane] = tile[c * 68 + lane];
  }
}

// ---- persistent scan ----
// 256 blocks x 256 threads; block bc owns 4 units (16 cols). Weights LDS-resident.
// h exchange: producers store write-through (sc0 sc1 -> LLC, no dirty L2);
// consumers read cached from a 16-deep ring; ONE acquire fence per 16 steps
// kills any stale L2/L1 copies (they are >=16 steps old by construction).
__global__ __launch_bounds__(256, 1) void k_scan(
    const unsigned short* __restrict__ xbf,
    const unsigned short* __restrict__ wp,
    const float* __restrict__ bias,
    float* __restrict__ out,
    unsigned* __restrict__ done1,
    unsigned* __restrict__ done2,
    unsigned short* __restrict__ hring) {
  __shared__ __align__(16) unsigned short Wlds[16 * W_STR];
  __shared__ __align__(16) unsigned short Ab[2][32 * A_STR];
  __shared__ float Gs[2][64 * G_STR];

  const int tid = threadIdx.x;
  const int lane = tid & 63;
  const int wave = tid >> 6;
  const int bc = blockIdx.x;
  const int grp = bc >> 4;
  const int arow = lane & 15;
  const int quad = lane >> 4;
  const int kh = wave & 1;
  const int rt_rel = wave >> 1;

  // one-time: weights -> LDS
  for (int i = tid; i < 16 * 192; i += 256) {
    int row = i / 192, o = i % 192;
    *(short8*)&Wlds[row * W_STR + o * 8] =
        *(const short8*)&wp[((size_t)bc * 16 + row) * 1536 + o * 8];
  }

  const int m = tid >> 2, ul = tid & 3;
  const int ug = bc * 4 + ul;
  const float bi = bias[ug], bff = bias[1024 + ug];
  const float bc_ = bias[2048 + ug], bo = bias[3072 + ug];
  float c_state = 0.f;
  __syncthreads();

  #pragma unroll 1
  for (int t = 0; t < T_STEPS; ++t) {
    f32x4 acc[2] = {{0.f, 0.f, 0.f, 0.f}, {0.f, 0.f, 0.f, 0.f}};

    // ---- X phase (no h dependency; overlaps barrier propagation) ----
    const unsigned short* xsrc = xbf + (size_t)t * 64 * 512;
    #pragma unroll
    for (int r = 0; r < 8; ++r) {
      int row = wave * 8 + r;
      g2l16(xsrc + (size_t)row * 512 + lane * 8, &Ab[0][row * A_STR]);
    }
    #pragma unroll
    for (int r = 0; r < 8; ++r) {
      int row = wave * 8 + r;
      g2l16(xsrc + (size_t)(32 + row) * 512 + lane * 8, &Ab[1][row * A_STR]);
    }
    __syncthreads();
    #pragma unroll
    for (int rh = 0; rh < 2; ++rh) {
      const unsigned short* Ap = &Ab[rh][(rt_rel * 16 + arow) * A_STR + kh * 256 + quad * 8];
      const unsigned short* Bp = &Wlds[arow * W_STR + kh * 256 + quad * 8];
      #pragma unroll
      for (int j = 0; j < 8; ++j) {
        short8 a = *(const short8*)(Ap + j * 32);
        short8 b = *(const short8*)(Bp + j * 32);
        acc[rh] = __builtin_amdgcn_mfma_f32_16x16x32_bf16(a, b, acc[rh], 0, 0, 0);
      }
    }

    // ---- wait for h_{t-1}: relaxed spin (LLC-routed agent atomic, no cache ops) ----
    if (t > 0 && tid == 0) {
      while (__hip_atomic_load(&done2[(t - 1) * 16], __ATOMIC_RELAXED,
                               __HIP_MEMORY_SCOPE_AGENT) != NGRP)
        __builtin_amdgcn_s_sleep(1);
    }
    __syncthreads();
    // windowed invalidate: stale ring lines are >=16 steps old; kill them
    // once per window instead of every step (64x fewer TCC maintenance ops)
    if (t > 0 && (t & (RING - 1)) == 0)
      __builtin_amdgcn_fence(__ATOMIC_ACQUIRE, "agent");

    // ---- H phase: 4 chunks, double-buffered, CACHED reads (L2 dedupes) ----
    const unsigned short* hsrc = hring + (size_t)(t & (RING - 1)) * SLOT_SHORTS;
    #pragma unroll
    for (int r = 0; r < 8; ++r) {
      int row = wave * 8 + r;
      g2l16(hsrc + (size_t)row * 1024 + lane * 8, &Ab[0][row * A_STR]);
    }
    __syncthreads();
    #pragma unroll
    for (int ph = 0; ph < 4; ++ph) {
      if (ph < 3) {
        int nrh = (ph + 1) >> 1, nks = (ph + 1) & 1;
        #pragma unroll
        for (int r = 0; r < 8; ++r) {
          int row = wave * 8 + r;
          g2l16(hsrc + (size_t)(nrh * 32 + row) * 1024 + nks * 512 + lane * 8,
                &Ab[(ph + 1) & 1][row * A_STR]);
        }
      }
      int rh = ph >> 1, ks = ph & 1;
      const unsigned short* Ap = &Ab[ph & 1][(rt_rel * 16 + arow) * A_STR + kh * 256 + quad * 8];
      const unsigned short* Bp = &Wlds[arow * W_STR + 512 + ks * 512 + kh * 256 + quad * 8];
      #pragma unroll
      for (int j = 0; j < 8; ++j) {
        short8 a = *(const short8*)(Ap + j * 32);
        short8 b = *(const short8*)(Bp + j * 32);
        acc[rh] = __builtin_amdgcn_mfma_f32_16x16x32_bf16(a, b, acc[rh], 0, 0, 0);
      }
      __syncthreads();
    }

    // ---- gates to LDS (C/D layout col=lane&15, row=quad*4+r) ----
    #pragma unroll
    for (int rh = 0; rh < 2; ++rh)
      #pragma unroll
      for (int r = 0; r < 4; ++r)
        Gs[kh][(rh * 32 + rt_rel * 16 + quad * 4 + r) * G_STR + arow] = acc[rh][r];
    __syncthreads();

    // ---- gate math ----
    float gi = Gs[0][m * G_STR + ul]      + Gs[1][m * G_STR + ul]      + bi;
    float gf = Gs[0][m * G_STR + 4 + ul]  + Gs[1][m * G_STR + 4 + ul]  + bff;
    float gc = Gs[0][m * G_STR + 8 + ul]  + Gs[1][m * G_STR + 8 + ul]  + bc_;
    float go = Gs[0][m * G_STR + 12 + ul] + Gs[1][m * G_STR + 12 + ul] + bo;
    float ig = 1.f / (1.f + __expf(-gi));
    float fg = 1.f / (1.f + __expf(-gf));
    float og = 1.f / (1.f + __expf(-go));
    float cb = tanhf(gc);
    c_state = fg * c_state + ig * cb;
    float h = og * tanhf(c_state);

    // write-through h store (sc0 sc1 -> LLC; producer L2 stays clean)
    float hpart = __shfl_xor(h, 1, 64);   // partner shares (m), ul^1
    unsigned short* hdst = hring + (size_t)((t + 1) & (RING - 1)) * SLOT_SHORTS;
    if ((ul & 1) == 0) {
      unsigned packed = (unsigned)f2bf(h) | ((unsigned)f2bf(hpart) << 16);
      __hip_atomic_store((unsigned*)hdst + ((m * 1024 + ug) >> 1), packed,
                         __ATOMIC_RELAXED, __HIP_MEMORY_SCOPE_SYSTEM);
    }
    if (t == T_STEPS - 1) {
      float* orow = out + (size_t)m * 3072 + ug;
      orow[0] = h;
      orow[1024] = h;
      orow[2048] = c_state;
    }
    __syncthreads();   // drains each wave's vmcnt: h stores are at LLC
    if (tid == 0) {
      unsigned prev = __hip_atomic_fetch_add(&done1[(t * 16 + grp) * 16], 1u,
                                             __ATOMIC_RELAXED,
                                             __HIP_MEMORY_SCOPE_AGENT);
      if (prev == NGRP - 1)
        __hip_atomic_fetch_add(&done2[t * 16], 1u, __ATOMIC_RELAXED,
                               __HIP_MEMORY_SCOPE_AGENT);
    }
  }
}

extern "C" void kernel_launch(void* const* d_in, const int* in_sizes, int n_in,
                              void* d_out, int out_size, void* d_ws, size_t ws_size,
                              hipStream_t stream) {
  const float* x  = (const float*)d_in[0];
  const float* Wx = (const float*)d_in[1];
  const float* Wh = (const float*)d_in[2];
  const float* b  = (const float*)d_in[3];
  float* out = (float*)d_out;
  char* ws = (char*)d_ws;
  unsigned* done1 = (unsigned*)(ws + OFF_DONE1);
  unsigned* done2 = (unsigned*)(ws + OFF_DONE2);
  unsigned short* hring = (unsigned short*)(ws + OFF_HRING);
  unsigned short* xbf = (unsigned short*)(ws + OFF_XBF);
  unsigned short* wp  = (unsigned short*)(ws + OFF_WPACK);

  hipMemsetAsync(d_ws, 0, MEMSET_BYTES, stream);
  k_xconv<<<8192, 256, 0, stream>>>(x, xbf);
  k_wpack<<<1536, 256, 0, stream>>>(Wx, Wh, wp);

  void* args[] = {&xbf, &wp, &b, &out, &done1, &done2, &hring};
  hipLaunchCooperativeKernel((void*)k_scan, dim3(256), dim3(256), args, 0, stream);
}